// Round 22
// baseline (676.921 us; speedup 1.0000x reference)
//
#include <hip/hip_runtime.h>
#include <hip/hip_bf16.h>
#include <cfloat>

// Problem constants
#define BB 8
#define NN 2048
#define KK 20
#define EPSV 1e-5f

typedef __attribute__((ext_vector_type(8))) short bf16x8v;
typedef __attribute__((ext_vector_type(4))) float f32x4v;

// fp32 -> bf16 (RNE, finite inputs)
__device__ __forceinline__ unsigned short f2bf(float f) {
  unsigned u = __float_as_uint(f);
  return (unsigned short)((u + 0x7fffu + ((u >> 16) & 1u)) >> 16);
}
__device__ __forceinline__ unsigned pack2bf(float a, float b) {
  return (unsigned)f2bf(a) | ((unsigned)f2bf(b) << 16);
}

// ---------------------------------------------------------------------------
// pack x (B,3,N) -> F0 (B,N,3) and xx (B,N)
__global__ __launch_bounds__(256) void pack_x(const float* __restrict__ x,
                                              float* __restrict__ F0,
                                              float* __restrict__ xx) {
  int b = blockIdx.x & 7;
  int n = (blockIdx.x >> 3) * 256 + threadIdx.x;
  if (n >= NN) return;
  float a = x[((size_t)b * 3 + 0) * NN + n];
  float c = x[((size_t)b * 3 + 1) * NN + n];
  float d = x[((size_t)b * 3 + 2) * NN + n];
  size_t r = (size_t)b * NN + n;
  F0[r * 3 + 0] = a;
  F0[r * 3 + 1] = c;
  F0[r * 3 + 2] = d;
  xx[r] = a * a + c * c + d * d;
}

// ---------------------------------------------------------------------------
// norms over C channels of F (pre-offset pointer), ld = ldf
__global__ __launch_bounds__(256) void norms_k(const float* __restrict__ F, int ldf, int C,
                                               float* __restrict__ xx) {
  int b = blockIdx.x & 7;
  int n = (blockIdx.x >> 3) * 256 + threadIdx.x;
  if (n >= NN) return;
  const float* f = F + ((size_t)b * NN + n) * ldf;
  float s = 0.f;
  for (int c = 0; c < C; c += 4) {
    float4 v = *(const float4*)(f + c);
    s += v.x * v.x + v.y * v.y + v.z * v.z + v.w * v.w;
  }
  xx[(size_t)b * NN + n] = s;
}

// ---------------------------------------------------------------------------
// 32x32 tiled transpose: src [b][n][C] (ld lds_) -> dst [b][c][n] (ld NN)
__global__ __launch_bounds__(256) void transpose_k(const float* __restrict__ src, int lds_, int C,
                                                   float* __restrict__ dst) {
  __shared__ float t[32][33];
  int b = blockIdx.x & 7;
  int tt = blockIdx.x >> 3;
  int n0 = (tt & 63) * 32, c0 = (tt >> 6) * 32;
  int tx = threadIdx.x & 31, ty = threadIdx.x >> 5;  // 32 x 8
#pragma unroll
  for (int i = 0; i < 32; i += 8) {
    t[ty + i][tx] = src[((size_t)b * NN + n0 + ty + i) * lds_ + c0 + tx];
  }
  __syncthreads();
#pragma unroll
  for (int i = 0; i < 32; i += 8) {
    dst[((size_t)b * C + c0 + ty + i) * NN + n0 + tx] = t[tx][ty + i];
  }
}

// ---------------------------------------------------------------------------
// Layer-1 kNN (C=3) v3: one wave per row, no LDS, no barriers. Minimal delta
// from the proven round-11 version: SAME scalar loads, SAME m-mapping
// (m = i*64+lane, used-bit = i), but the load loop is split from the top-3
// insert loop so all 128 independent loads batch into flight (no serial
// insert chain interleaved). Identical selection semantics -> identical idx.
__global__ __launch_bounds__(512) void knn1_reg(const float* __restrict__ x,  // [b][3][NN]
                                                const float* __restrict__ xx,
                                                int* __restrict__ idx) {
  int b = blockIdx.x & 7;
  int r0 = (blockIdx.x >> 3) * 8;
  int wv = threadIdx.x >> 6, lane = threadIdx.x & 63;
  int r = r0 + wv;
  const float* x0 = x + (size_t)b * 3 * NN;
  const float* x1 = x0 + NN;
  const float* x2 = x0 + 2 * NN;
  const float* xxb = xx + (size_t)b * NN;
  float xr0 = x0[r], xr1 = x1[r], xr2 = x2[r];
  float rn = xxb[r];

  // phase 1: distances only (no dependent insert chain in this loop)
  float f[32];
#pragma unroll
  for (int i = 0; i < 32; ++i) {
    int m = i * 64 + lane;
    float acc = xr0 * x0[m];
    acc += xr1 * x1[m];
    acc += xr2 * x2[m];
    f[i] = (2.f * acc - rn) - xxb[m];
  }

  // phase 2: build per-lane top-3 cache (ascending i -> min-m kept on ties)
  float v1 = -FLT_MAX, v2 = -FLT_MAX, v3 = -FLT_MAX;
  int m1 = 0x7fffffff, m2 = 0x7fffffff, m3 = 0x7fffffff;
#pragma unroll
  for (int i = 0; i < 32; ++i) {
    float v = f[i];
    int m = i * 64 + lane;
    if (v > v3) {
      if (v > v2) {
        v3 = v2; m3 = m2;
        if (v > v1) { v2 = v1; m2 = m1; v1 = v; m1 = m; }
        else { v2 = v; m2 = m; }
      } else { v3 = v; m3 = m; }
    }
  }

  unsigned used = 0u;
  int navail = 3;
  int myidx = 0;
  for (int it = 0; it < KK; ++it) {
    float bv = v1;
    int bm = m1;
#pragma unroll
    for (int off = 32; off > 0; off >>= 1) {
      float ov = __shfl_xor(bv, off);
      int om = __shfl_xor(bm, off);
      if (ov > bv || (ov == bv && om < bm)) { bv = ov; bm = om; }
    }
    if (lane == it) myidx = bm;
    if (m1 == bm) {  // m encodes lane -> exactly the winning lane
      used |= 1u << (m1 >> 6);
      v1 = v2; m1 = m2;
      v2 = v3; m2 = m3;
      v3 = -FLT_MAX; m3 = 0x7fffffff;
      if (--navail == 0) {  // rare: rebuild from registers
        v1 = v2 = v3 = -FLT_MAX;
        m1 = m2 = m3 = 0x7fffffff;
#pragma unroll
        for (int i = 0; i < 32; ++i) {
          if (used & (1u << i)) continue;
          float v = f[i];
          int m = i * 64 + lane;
          if (v > v3) {
            if (v > v2) {
              v3 = v2; m3 = m2;
              if (v > v1) { v2 = v1; m2 = m1; v1 = v; m1 = m; }
              else { v2 = v; m2 = m; }
            } else { v3 = v; m3 = m; }
          }
        }
        navail = 3;
      }
    }
  }
  if (lane < KK) idx[((size_t)b * NN + r) * KK + lane] = myidx;
}

// ---------------------------------------------------------------------------
// Distance GEMM (round-16 v4 body, zmask/zshift grid): D[zi][i][j] =
// (2*sum_c FT[c][i]*FT[c][j] - xx[i]) - xx[j]. 128x128 tile, 256 threads,
// 8x8 micro-tile, single-buffered LDS (~52 VGPR), tj-fast coalesced stores.
// c-ascending accumulation per (i,j) -> bit-identical D vs all prior rounds.
template <int C>
__global__ __launch_bounds__(256) void dist_gemm(const float* __restrict__ FT,
                                                 const float* __restrict__ xx,
                                                 float* __restrict__ D,
                                                 int zmask, int zshift) {
  __shared__ __align__(16) float Is[8][128];
  __shared__ __align__(16) float Js[8][128];
  int zi = blockIdx.x & zmask;
  int tt = blockIdx.x >> zshift;
  int i0 = (tt & 15) * 128, j0 = (tt >> 4) * 128;
  const float* FTb = FT + (size_t)zi * C * NN;
  const float* xxb = xx + (size_t)zi * NN;
  float* Db = D + (size_t)zi * NN * NN;
  int tid = threadIdx.x;
  int tj = tid & 15, ti = tid >> 4;        // tj fast -> contiguous j stores
  int sc = tid >> 5, su = (tid & 31) * 4;  // staging: c-row, 4-col group

  float acc[8][8];
#pragma unroll
  for (int ii = 0; ii < 8; ++ii)
#pragma unroll
    for (int jj = 0; jj < 8; ++jj) acc[ii][jj] = 0.f;

  for (int c0 = 0; c0 < C; c0 += 8) {
    *(float4*)&Is[sc][su] = *(const float4*)&FTb[(size_t)(c0 + sc) * NN + i0 + su];
    *(float4*)&Js[sc][su] = *(const float4*)&FTb[(size_t)(c0 + sc) * NN + j0 + su];
    __syncthreads();
#pragma unroll
    for (int k = 0; k < 8; ++k) {
      float4 a0 = *(const float4*)&Is[k][ti * 4];
      float4 a1 = *(const float4*)&Is[k][64 + ti * 4];
      float4 b0 = *(const float4*)&Js[k][tj * 4];
      float4 b1 = *(const float4*)&Js[k][64 + tj * 4];
      float ai[8] = {a0.x, a0.y, a0.z, a0.w, a1.x, a1.y, a1.z, a1.w};
      float bj[8] = {b0.x, b0.y, b0.z, b0.w, b1.x, b1.y, b1.z, b1.w};
#pragma unroll
      for (int ii = 0; ii < 8; ++ii)
#pragma unroll
        for (int jj = 0; jj < 8; ++jj) acc[ii][jj] += ai[ii] * bj[jj];
    }
    __syncthreads();
  }

  // epilogue: d = (2*dot - xx_i) - xx_j ; contiguous j-major float4 stores
  float4 xi03 = *(const float4*)&xxb[i0 + ti * 4];
  float4 xi47 = *(const float4*)&xxb[i0 + 64 + ti * 4];
  float4 xj03 = *(const float4*)&xxb[j0 + tj * 4];
  float4 xj47 = *(const float4*)&xxb[j0 + 64 + tj * 4];
  float xi[8] = {xi03.x, xi03.y, xi03.z, xi03.w, xi47.x, xi47.y, xi47.z, xi47.w};
  float xj[8] = {xj03.x, xj03.y, xj03.z, xj03.w, xj47.x, xj47.y, xj47.z, xj47.w};
#pragma unroll
  for (int ii = 0; ii < 8; ++ii) {
    int i_ = i0 + (ii < 4 ? ti * 4 + ii : 64 + ti * 4 + (ii - 4));
    float4 o0, o1;
    float* p0 = (float*)&o0;
    float* p1 = (float*)&o1;
#pragma unroll
    for (int jj = 0; jj < 4; ++jj) p0[jj] = (2.f * acc[ii][jj] - xi[ii]) - xj[jj];
#pragma unroll
    for (int jj = 0; jj < 4; ++jj) p1[jj] = (2.f * acc[ii][jj + 4] - xi[ii]) - xj[jj + 4];
    *(float4*)&Db[(size_t)i_ * NN + j0 + tj * 4] = o0;
    *(float4*)&Db[(size_t)i_ * NN + j0 + 64 + tj * 4] = o1;
  }
}

// ---------------------------------------------------------------------------
// Selection from D: one wave per row; row loaded as 8x float4 in a dedicated
// loop BEFORE the top-3 insert scan. m = i*256 + lane*4 + j; (v desc, m asc)
// butterfly -> exact top-20 of bit-identical D.
__global__ __launch_bounds__(512) void sel_rows(const float* __restrict__ D,
                                                int* __restrict__ idx,
                                                int zmask, int zshift) {
  int zi = blockIdx.x & zmask;
  int wv = threadIdx.x >> 6, lane = threadIdx.x & 63;
  int r = (blockIdx.x >> zshift) * 8 + wv;
  const float* row = D + (size_t)zi * NN * NN + (size_t)r * NN;

  // phase 1: 8 wide loads, no dependent consumer between them
  float4 g[8];
#pragma unroll
  for (int i = 0; i < 8; ++i) g[i] = *(const float4*)&row[i * 256 + lane * 4];

  // phase 2: build per-lane top-3 cache (ascending m per lane)
  float f[32];
  float v1 = -FLT_MAX, v2 = -FLT_MAX, v3 = -FLT_MAX;
  int m1 = 0x7fffffff, m2 = 0x7fffffff, m3 = 0x7fffffff;
#pragma unroll
  for (int i = 0; i < 8; ++i) {
    const float* gv = (const float*)&g[i];
#pragma unroll
    for (int j = 0; j < 4; ++j) {
      float v = gv[j];
      int m = i * 256 + lane * 4 + j;
      f[i * 4 + j] = v;
      if (v > v3) {  // strict >, ascending m -> min-m kept on ties
        if (v > v2) {
          v3 = v2; m3 = m2;
          if (v > v1) { v2 = v1; m2 = m1; v1 = v; m1 = m; }
          else { v2 = v; m2 = m; }
        } else { v3 = v; m3 = m; }
      }
    }
  }

  unsigned used = 0u;
  int navail = 3;
  int myidx = 0;
  for (int it = 0; it < KK; ++it) {
    float bv = v1;
    int bm = m1;
#pragma unroll
    for (int off = 32; off > 0; off >>= 1) {
      float ov = __shfl_xor(bv, off);
      int om = __shfl_xor(bm, off);
      if (ov > bv || (ov == bv && om < bm)) { bv = ov; bm = om; }
    }
    if (lane == it) myidx = bm;
    if (m1 == bm) {  // lane(m) = (m>>2)&63 -> exactly the winning lane
      used |= 1u << (((unsigned)m1 >> 8) * 4 + ((unsigned)m1 & 3));  // slot i*4+j
      v1 = v2; m1 = m2;
      v2 = v3; m2 = m3;
      v3 = -FLT_MAX; m3 = 0x7fffffff;
      if (--navail == 0) {  // rare: rebuild from registers
        v1 = v2 = v3 = -FLT_MAX;
        m1 = m2 = m3 = 0x7fffffff;
#pragma unroll
        for (int s = 0; s < 32; ++s) {
          if (used & (1u << s)) continue;
          float v = f[s];
          int m = (s >> 2) * 256 + lane * 4 + (s & 3);
          if (v > v3) {
            if (v > v2) {
              v3 = v2; m3 = m2;
              if (v > v1) { v2 = v1; m2 = m1; v1 = v; m1 = m; }
              else { v2 = v; m2 = m; }
            } else { v3 = v; m3 = m; }
          }
        }
        navail = 3;
      }
    }
  }
  if (lane < KK) idx[(size_t)zi * NN * KK + (size_t)r * KK + lane] = myidx;
}

// ---------------------------------------------------------------------------
// prep: split w (O,2C) -> Wa (O,C), Wd = Wb - Wa; sv = g/sqrt(v+eps);
//       tq = (bias - m)*sv + be.  (C==0 -> only sv/tq, for the final layer)
__global__ __launch_bounds__(256) void prep_edge(const float* __restrict__ w,
                                                 const float* __restrict__ bias,
                                                 const float* __restrict__ g,
                                                 const float* __restrict__ be,
                                                 const float* __restrict__ m,
                                                 const float* __restrict__ v,
                                                 float* __restrict__ Wa, float* __restrict__ Wd,
                                                 float* __restrict__ sv, float* __restrict__ tq,
                                                 int O, int C) {
  int i = blockIdx.x * 256 + threadIdx.x;
  if (i < O * C) {
    int o = i / C, c = i % C;
    float wa = w[(size_t)o * 2 * C + c];
    float wb = w[(size_t)o * 2 * C + C + c];
    Wa[i] = wa;
    Wd[i] = wb - wa;
  }
  if (i < O) {
    float s = g[i] / sqrtf(v[i] + EPSV);
    sv[i] = s;
    tq[i] = (bias[i] - m[i]) * s + be[i];
  }
}

// ---------------------------------------------------------------------------
// fp32 tiled dual GEMM (layers 1-2: outputs feed kNN -> keep fp32)
template <bool DUAL>
__global__ __launch_bounds__(256) void gemm_pq(const float* __restrict__ F, int ldf, int C,
                                               const float* __restrict__ Wa,
                                               const float* __restrict__ Wd,
                                               const float* __restrict__ sv,
                                               const float* __restrict__ tp,
                                               const float* __restrict__ tq,
                                               float* __restrict__ P, float* __restrict__ Q,
                                               int O) {
  __shared__ __align__(16) float Fs[8][64];
  __shared__ __align__(16) float Was[8][64];
  __shared__ __align__(16) float Wds[8][64];
  int b = blockIdx.x & 7;
  int tt = blockIdx.x >> 3;
  int n0 = (tt & 31) * 64, o0 = (tt >> 5) * 64;
  int tid = threadIdx.x;
  int tn = tid & 15, to = tid >> 4;
  float accP[4][4] = {{0.f}};
  float accQ[4][4] = {{0.f}};
  const float* Fb = F + (size_t)b * NN * ldf;

  for (int c0 = 0; c0 < C; c0 += 8) {
    for (int e = tid; e < 512; e += 256) {
      int n = e >> 3, k = e & 7, c = c0 + k;
      Fs[k][n] = (c < C) ? Fb[(size_t)(n0 + n) * ldf + c] : 0.f;
      Was[k][n] = (c < C) ? Wa[(size_t)(o0 + n) * C + c] : 0.f;
      if (DUAL) Wds[k][n] = (c < C) ? Wd[(size_t)(o0 + n) * C + c] : 0.f;
    }
    __syncthreads();
#pragma unroll
    for (int k = 0; k < 8; ++k) {
      float4 fq = *(const float4*)&Fs[k][tn * 4];
      float4 aq = *(const float4*)&Was[k][to * 4];
      float fa[4] = {fq.x, fq.y, fq.z, fq.w};
      float aa[4] = {aq.x, aq.y, aq.z, aq.w};
#pragma unroll
      for (int i = 0; i < 4; ++i)
#pragma unroll
        for (int j = 0; j < 4; ++j) accP[i][j] += fa[i] * aa[j];
      if (DUAL) {
        float4 dq = *(const float4*)&Wds[k][to * 4];
        float da[4] = {dq.x, dq.y, dq.z, dq.w};
#pragma unroll
        for (int i = 0; i < 4; ++i)
#pragma unroll
          for (int j = 0; j < 4; ++j) accQ[i][j] += fa[i] * da[j];
      }
    }
    __syncthreads();
  }

#pragma unroll
  for (int j = 0; j < 4; ++j) {
    int o = o0 + to * 4 + j;
    float s = sv[o];
    float tpv = (tp != nullptr) ? tp[o] : 0.f;
    float tqv = DUAL ? tq[o] : 0.f;
#pragma unroll
    for (int i = 0; i < 4; ++i) {
      int n = n0 + tn * 4 + i;
      size_t base = ((size_t)b * NN + n) * O + o;
      P[base] = accP[i][j] * s + tpv;
      if (DUAL) Q[base] = accQ[i][j] * s + tqv;
    }
  }
}

// ---------------------------------------------------------------------------
// MFMA bf16 GEMM (fp32 in/out, bf16 staging): layer-3 dual GEMM + final GEMM.
template <int K, bool DUAL>
__global__ __launch_bounds__(256) void gemm_mfma(const float* __restrict__ A, int lda,
                                                 const float* __restrict__ Bw,
                                                 const float* __restrict__ Dw,
                                                 const float* __restrict__ sv,
                                                 const float* __restrict__ tp,
                                                 const float* __restrict__ tq,
                                                 float* __restrict__ P, float* __restrict__ Q,
                                                 int O) {
  __shared__ unsigned short As[128 * 40];
  __shared__ unsigned short Bs[64 * 40];
  __shared__ unsigned short Ds[64 * 40];
  int b = blockIdx.x & 7;
  int tt = blockIdx.x >> 3;
  int nTN = O >> 6;
  int n0 = (tt / nTN) * 128;
  int o0 = (tt % nTN) * 64;
  int tid = threadIdx.x;
  int wv = tid >> 6, lane = tid & 63;
  int wm = wv & 1, wn = wv >> 1;
  const float* Ab = A + (size_t)b * NN * lda;

  f32x4v accP[4][2];
  f32x4v accQ[4][2];
#pragma unroll
  for (int m = 0; m < 4; ++m)
#pragma unroll
    for (int of = 0; of < 2; ++of) {
      accP[m][of] = (f32x4v){0.f, 0.f, 0.f, 0.f};
      if constexpr (DUAL) accQ[m][of] = (f32x4v){0.f, 0.f, 0.f, 0.f};
    }

  for (int ks = 0; ks < K; ks += 32) {
    for (int i = tid; i < 1024; i += 256) {
      int row = i >> 3, k4 = (i & 7) * 4;
      float4 v = *(const float4*)&Ab[(size_t)(n0 + row) * lda + ks + k4];
      uint2 p;
      p.x = pack2bf(v.x, v.y);
      p.y = pack2bf(v.z, v.w);
      *(uint2*)&As[row * 40 + k4] = p;
    }
    for (int i = tid; i < 512; i += 256) {
      int row = i >> 3, k4 = (i & 7) * 4;
      float4 v = *(const float4*)&Bw[(size_t)(o0 + row) * K + ks + k4];
      uint2 p;
      p.x = pack2bf(v.x, v.y);
      p.y = pack2bf(v.z, v.w);
      *(uint2*)&Bs[row * 40 + k4] = p;
      if constexpr (DUAL) {
        float4 d = *(const float4*)&Dw[(size_t)(o0 + row) * K + ks + k4];
        uint2 q;
        q.x = pack2bf(d.x, d.y);
        q.y = pack2bf(d.z, d.w);
        *(uint2*)&Ds[row * 40 + k4] = q;
      }
    }
    __syncthreads();

    int krow = (lane >> 4) * 8;
    bf16x8v af[4], bfr[2], dfr[2];
#pragma unroll
    for (int m = 0; m < 4; ++m)
      af[m] = *(const bf16x8v*)&As[(wm * 64 + m * 16 + (lane & 15)) * 40 + krow];
#pragma unroll
    for (int of = 0; of < 2; ++of) {
      bfr[of] = *(const bf16x8v*)&Bs[(wn * 32 + of * 16 + (lane & 15)) * 40 + krow];
      if constexpr (DUAL)
        dfr[of] = *(const bf16x8v*)&Ds[(wn * 32 + of * 16 + (lane & 15)) * 40 + krow];
    }
#pragma unroll
    for (int m = 0; m < 4; ++m)
#pragma unroll
      for (int of = 0; of < 2; ++of) {
        accP[m][of] = __builtin_amdgcn_mfma_f32_16x16x32_bf16(af[m], bfr[of], accP[m][of], 0, 0, 0);
        if constexpr (DUAL)
          accQ[m][of] = __builtin_amdgcn_mfma_f32_16x16x32_bf16(af[m], dfr[of], accQ[m][of], 0, 0, 0);
      }
    __syncthreads();
  }

#pragma unroll
  for (int of = 0; of < 2; ++of) {
    int o = o0 + wn * 32 + of * 16 + (lane & 15);
    float s = sv[o];
    float bp = (tp != nullptr) ? tp[o] : 0.f;
    float bq = DUAL ? tq[o] : 0.f;
#pragma unroll
    for (int m = 0; m < 4; ++m) {
#pragma unroll
      for (int r = 0; r < 4; ++r) {
        int n = n0 + wm * 64 + m * 16 + (lane >> 4) * 4 + r;
        size_t base = ((size_t)b * NN + n) * O + o;
        P[base] = accP[m][of][r] * s + bp;
        if constexpr (DUAL) Q[base] = accQ[m][of][r] * s + bq;
      }
    }
  }
}

// ---------------------------------------------------------------------------
// gather-max: H[b][n][c0+o] = max(0, max_k (P[b][idx[n][k]][o] + Q[b][n][o]))
template <int O>
__global__ __launch_bounds__(256) void gather_max2(const float* __restrict__ P,
                                                   const float* __restrict__ Q,
                                                   const int* __restrict__ idx,
                                                   float* __restrict__ H, int c0) {
  constexpr int NPB = 256 / O;
  int b = blockIdx.x & 7;
  int sub = threadIdx.x / O, o = threadIdx.x % O;
  int n = (blockIdx.x >> 3) * NPB + sub;
  const int* id = idx + ((size_t)b * NN + n) * KK;
  float q = Q[((size_t)b * NN + n) * O + o];
  float best = -FLT_MAX;
#pragma unroll 4
  for (int k = 0; k < KK; ++k) {
    int j = id[k];
    float v = P[((size_t)b * NN + j) * O + o] + q;
    best = fmaxf(best, v);
  }
  best = fmaxf(best, 0.f);  // relu (before max == after max)
  H[((size_t)b * NN + n) * 448 + c0 + o] = best;
}

// ---------------------------------------------------------------------------
// final reduce: out[b][o] = max over n-chunk, via uint atomicMax (values >= 0)
__global__ __launch_bounds__(256) void reduce_max_part(const float* __restrict__ Z,
                                                       unsigned* __restrict__ out) {
  int b = blockIdx.x & 7;
  int tt = blockIdx.x >> 3;
  int o = (tt & 1) * 256 + threadIdx.x;  // o < 512
  int n0 = (tt >> 1) * 256;
  float m = 0.f;  // relu floor
  for (int n = n0; n < n0 + 256; ++n) {
    float v = Z[((size_t)b * NN + n) * 512 + o];
    m = fmaxf(m, v);
  }
  atomicMax(&out[(size_t)b * 512 + o], __float_as_uint(m));
}

// ---------------------------------------------------------------------------
extern "C" void kernel_launch(void* const* d_in, const int* in_sizes, int n_in,
                              void* d_out, int out_size, void* d_ws, size_t ws_size,
                              hipStream_t stream) {
  const float* x = (const float*)d_in[0];
  const float* w1 = (const float*)d_in[1];
  const float* b1 = (const float*)d_in[2];
  const float* g1 = (const float*)d_in[3];
  const float* be1 = (const float*)d_in[4];
  const float* m1 = (const float*)d_in[5];
  const float* v1 = (const float*)d_in[6];
  const float* w2 = (const float*)d_in[7];
  const float* b2 = (const float*)d_in[8];
  const float* g2 = (const float*)d_in[9];
  const float* be2 = (const float*)d_in[10];
  const float* m2 = (const float*)d_in[11];
  const float* v2 = (const float*)d_in[12];
  const float* w3 = (const float*)d_in[13];
  const float* b3 = (const float*)d_in[14];
  const float* g3 = (const float*)d_in[15];
  const float* be3 = (const float*)d_in[16];
  const float* m3 = (const float*)d_in[17];
  const float* v3 = (const float*)d_in[18];
  const float* wo = (const float*)d_in[19];
  const float* bo = (const float*)d_in[20];
  const float* go = (const float*)d_in[21];
  const float* beo = (const float*)d_in[22];
  const float* mo = (const float*)d_in[23];
  const float* vo = (const float*)d_in[24];

  char* ws = (char*)d_ws;
  float* H = (float*)(ws + 0);              // 29360128
  float* F0 = (float*)(ws + 29360128);      // 196608
  float* xx = (float*)(ws + 29556736);      // 65536
  int* idx = (int*)(ws + 29622272);         // 1310720
  float* P = (float*)(ws + 30932992);       // 16777216
  float* Q = (float*)(ws + 47710208);       // 16777216 (aliased: FT + Z)
  float* Wa = (float*)(ws + 64487424);      // 131072
  float* Wd = (float*)(ws + 64618496);      // 131072
  float* sv = (float*)(ws + 64749568);      // 4096
  float* tq = (float*)(ws + 64753664);      // 4096
  float* Z = P;
  float* FT = Q;

  // D buffer: full 8-batch (134MB) if workspace allows, else 1-batch aliasing P
  bool bigws = ws_size >= (size_t)198975488;
  float* Dbuf = bigws ? (float*)(ws + 64757760) : P;

  dim3 blk(256);

  pack_x<<<dim3(8 * 8), blk, 0, stream>>>(x, F0, xx);

  // ---- layer 1: C=3, O=64  (x is already [b][c][n]; knn1_reg reads it directly)
  prep_edge<<<dim3(1), blk, 0, stream>>>(w1, b1, g1, be1, m1, v1, Wa, Wd, sv, tq, 64, 3);
  knn1_reg<<<dim3(8 * NN / 8), dim3(512), 0, stream>>>(x, xx, idx);
  gemm_pq<true><<<dim3(8 * 32 * 1), blk, 0, stream>>>(F0, 3, 3, Wa, Wd, sv, nullptr, tq, P, Q, 64);
  gather_max2<64><<<dim3(8 * NN / 4), blk, 0, stream>>>(P, Q, idx, H, 0);
  norms_k<<<dim3(8 * 8), blk, 0, stream>>>(H, 448, 64, xx);

  // ---- layer 2: C=64, O=128
  prep_edge<<<dim3(32), blk, 0, stream>>>(w2, b2, g2, be2, m2, v2, Wa, Wd, sv, tq, 128, 64);
  transpose_k<<<dim3(8 * 64 * 2), blk, 0, stream>>>(H, 448, 64, FT);
  if (bigws) {
    dist_gemm<64><<<dim3(8 * 16 * 16), blk, 0, stream>>>(FT, xx, Dbuf, 7, 3);
    sel_rows<<<dim3(8 * NN / 8), dim3(512), 0, stream>>>(Dbuf, idx, 7, 3);
  } else {
    for (int bb = 0; bb < BB; ++bb) {
      dist_gemm<64><<<dim3(16 * 16), blk, 0, stream>>>(FT + (size_t)bb * 64 * NN,
                                                       xx + (size_t)bb * NN, Dbuf, 0, 0);
      sel_rows<<<dim3(NN / 8), dim3(512), 0, stream>>>(Dbuf, idx + (size_t)bb * NN * KK, 0, 0);
    }
  }
  gemm_pq<true><<<dim3(8 * 32 * 2), blk, 0, stream>>>(H, 448, 64, Wa, Wd, sv, nullptr, tq, P, Q, 128);
  gather_max2<128><<<dim3(8 * NN / 2), blk, 0, stream>>>(P, Q, idx, H, 64);
  norms_k<<<dim3(8 * 8), blk, 0, stream>>>(H + 64, 448, 128, xx);

  // ---- layer 3: C=128, O=256
  prep_edge<<<dim3(128), blk, 0, stream>>>(w3, b3, g3, be3, m3, v3, Wa, Wd, sv, tq, 256, 128);
  transpose_k<<<dim3(8 * 64 * 4), blk, 0, stream>>>(H + 64, 448, 128, FT);
  if (bigws) {
    dist_gemm<128><<<dim3(8 * 16 * 16), blk, 0, stream>>>(FT, xx, Dbuf, 7, 3);
    sel_rows<<<dim3(8 * NN / 8), dim3(512), 0, stream>>>(Dbuf, idx, 7, 3);
  } else {
    for (int bb = 0; bb < BB; ++bb) {
      dist_gemm<128><<<dim3(16 * 16), blk, 0, stream>>>(FT + (size_t)bb * 128 * NN,
                                                        xx + (size_t)bb * NN, Dbuf, 0, 0);
      sel_rows<<<dim3(NN / 8), dim3(512), 0, stream>>>(Dbuf, idx + (size_t)bb * NN * KK, 0, 0);
    }
  }
  gemm_mfma<128, true><<<dim3(8 * 16 * 4), blk, 0, stream>>>(H + 64, 448, Wa, Wd, sv, nullptr, tq, P, Q, 256);
  gather_max2<256><<<dim3(8 * NN), blk, 0, stream>>>(P, Q, idx, H, 192);

  // ---- final linear: C=448, O=512 (MFMA bf16; BN folded via sv/tq)
  prep_edge<<<dim3(2), blk, 0, stream>>>(nullptr, bo, go, beo, mo, vo, nullptr, nullptr, sv, tq, 512, 0);
  gemm_mfma<448, false><<<dim3(8 * 16 * 8), blk, 0, stream>>>(H, 448, wo, nullptr, sv, tq, nullptr, Z, nullptr, 512);

  hipMemsetAsync(d_out, 0, (size_t)out_size * sizeof(float), stream);
  reduce_max_part<<<dim3(8 * 16), blk, 0, stream>>>(Z, (unsigned*)d_out);
}

// Round 23
// 633.274 us; speedup vs baseline: 1.0689x; 1.0689x over previous
//
#include <hip/hip_runtime.h>
#include <hip/hip_bf16.h>
#include <cfloat>

// Problem constants
#define BB 8
#define NN 2048
#define KK 20
#define EPSV 1e-5f

typedef __attribute__((ext_vector_type(8))) short bf16x8v;
typedef __attribute__((ext_vector_type(4))) float f32x4v;

// fp32 -> bf16 (RNE, finite inputs)
__device__ __forceinline__ unsigned short f2bf(float f) {
  unsigned u = __float_as_uint(f);
  return (unsigned short)((u + 0x7fffu + ((u >> 16) & 1u)) >> 16);
}
__device__ __forceinline__ unsigned pack2bf(float a, float b) {
  return (unsigned)f2bf(a) | ((unsigned)f2bf(b) << 16);
}

// ---------------------------------------------------------------------------
// pack x (B,3,N) -> F0 (B,N,3) and xx (B,N)
__global__ __launch_bounds__(256) void pack_x(const float* __restrict__ x,
                                              float* __restrict__ F0,
                                              float* __restrict__ xx) {
  int b = blockIdx.x & 7;
  int n = (blockIdx.x >> 3) * 256 + threadIdx.x;
  if (n >= NN) return;
  float a = x[((size_t)b * 3 + 0) * NN + n];
  float c = x[((size_t)b * 3 + 1) * NN + n];
  float d = x[((size_t)b * 3 + 2) * NN + n];
  size_t r = (size_t)b * NN + n;
  F0[r * 3 + 0] = a;
  F0[r * 3 + 1] = c;
  F0[r * 3 + 2] = d;
  xx[r] = a * a + c * c + d * d;
}

// ---------------------------------------------------------------------------
// norms over C channels of F (pre-offset pointer), ld = ldf
__global__ __launch_bounds__(256) void norms_k(const float* __restrict__ F, int ldf, int C,
                                               float* __restrict__ xx) {
  int b = blockIdx.x & 7;
  int n = (blockIdx.x >> 3) * 256 + threadIdx.x;
  if (n >= NN) return;
  const float* f = F + ((size_t)b * NN + n) * ldf;
  float s = 0.f;
  for (int c = 0; c < C; c += 4) {
    float4 v = *(const float4*)(f + c);
    s += v.x * v.x + v.y * v.y + v.z * v.z + v.w * v.w;
  }
  xx[(size_t)b * NN + n] = s;
}

// ---------------------------------------------------------------------------
// 32x32 tiled transpose: src [b][n][C] (ld lds_) -> dst [b][c][n] (ld NN)
__global__ __launch_bounds__(256) void transpose_k(const float* __restrict__ src, int lds_, int C,
                                                   float* __restrict__ dst) {
  __shared__ float t[32][33];
  int b = blockIdx.x & 7;
  int tt = blockIdx.x >> 3;
  int n0 = (tt & 63) * 32, c0 = (tt >> 6) * 32;
  int tx = threadIdx.x & 31, ty = threadIdx.x >> 5;  // 32 x 8
#pragma unroll
  for (int i = 0; i < 32; i += 8) {
    t[ty + i][tx] = src[((size_t)b * NN + n0 + ty + i) * lds_ + c0 + tx];
  }
  __syncthreads();
#pragma unroll
  for (int i = 0; i < 32; i += 8) {
    dst[((size_t)b * C + c0 + ty + i) * NN + n0 + tx] = t[tx][ty + i];
  }
}

// ---------------------------------------------------------------------------
// Layer-1 kNN (C=3), round-11 proven version: one wave per row, no LDS, no
// barriers. Per-lane top-3 cache built inline with the distance pass (44
// VGPR, best measured); 20x butterfly argmax; rebuild from registers on a
// lane's 3rd win (rare).
__global__ __launch_bounds__(512) void knn1_reg(const float* __restrict__ x,  // [b][3][NN]
                                                const float* __restrict__ xx,
                                                int* __restrict__ idx) {
  int b = blockIdx.x & 7;
  int r0 = (blockIdx.x >> 3) * 8;
  int wv = threadIdx.x >> 6, lane = threadIdx.x & 63;
  int r = r0 + wv;
  const float* x0 = x + (size_t)b * 3 * NN;
  const float* x1 = x0 + NN;
  const float* x2 = x0 + 2 * NN;
  const float* xxb = xx + (size_t)b * NN;
  float xr0 = x0[r], xr1 = x1[r], xr2 = x2[r];
  float rn = xxb[r];

  float f[32];
  float v1 = -FLT_MAX, v2 = -FLT_MAX, v3 = -FLT_MAX;
  int m1 = 0x7fffffff, m2 = 0x7fffffff, m3 = 0x7fffffff;
#pragma unroll
  for (int i = 0; i < 32; ++i) {
    int m = i * 64 + lane;
    float acc = xr0 * x0[m];
    acc += xr1 * x1[m];
    acc += xr2 * x2[m];
    float d = (2.f * acc - rn) - xxb[m];
    f[i] = d;
    if (d > v3) {  // strict > , ascending i -> min-m kept on ties
      if (d > v2) {
        v3 = v2; m3 = m2;
        if (d > v1) { v2 = v1; m2 = m1; v1 = d; m1 = m; }
        else { v2 = d; m2 = m; }
      } else { v3 = d; m3 = m; }
    }
  }

  unsigned used = 0u;
  int navail = 3;
  int myidx = 0;
  for (int it = 0; it < KK; ++it) {
    float bv = v1;
    int bm = m1;
#pragma unroll
    for (int off = 32; off > 0; off >>= 1) {
      float ov = __shfl_xor(bv, off);
      int om = __shfl_xor(bm, off);
      if (ov > bv || (ov == bv && om < bm)) { bv = ov; bm = om; }
    }
    if (lane == it) myidx = bm;
    if (m1 == bm) {  // m encodes lane -> exactly the winning lane
      used |= 1u << (m1 >> 6);
      v1 = v2; m1 = m2;
      v2 = v3; m2 = m3;
      v3 = -FLT_MAX; m3 = 0x7fffffff;
      if (--navail == 0) {  // rare: lane won 3 times -> rebuild from registers
        v1 = v2 = v3 = -FLT_MAX;
        m1 = m2 = m3 = 0x7fffffff;
#pragma unroll
        for (int i = 0; i < 32; ++i) {
          if (used & (1u << i)) continue;
          float v = f[i];
          int m = i * 64 + lane;
          if (v > v3) {
            if (v > v2) {
              v3 = v2; m3 = m2;
              if (v > v1) { v2 = v1; m2 = m1; v1 = v; m1 = m; }
              else { v2 = v; m2 = m; }
            } else { v3 = v; m3 = m; }
          }
        }
        navail = 3;
      }
    }
  }
  if (lane < KK) idx[((size_t)b * NN + r) * KK + lane] = myidx;
}

// ---------------------------------------------------------------------------
// Distance GEMM (round-16 v4 body, zmask/zshift grid): D[zi][i][j] =
// (2*sum_c FT[c][i]*FT[c][j] - xx[i]) - xx[j]. 128x128 tile, 256 threads,
// 8x8 micro-tile, single-buffered LDS (~52 VGPR), tj-fast coalesced stores.
// c-ascending accumulation per (i,j) -> bit-identical D vs all prior rounds.
template <int C>
__global__ __launch_bounds__(256) void dist_gemm(const float* __restrict__ FT,
                                                 const float* __restrict__ xx,
                                                 float* __restrict__ D,
                                                 int zmask, int zshift) {
  __shared__ __align__(16) float Is[8][128];
  __shared__ __align__(16) float Js[8][128];
  int zi = blockIdx.x & zmask;
  int tt = blockIdx.x >> zshift;
  int i0 = (tt & 15) * 128, j0 = (tt >> 4) * 128;
  const float* FTb = FT + (size_t)zi * C * NN;
  const float* xxb = xx + (size_t)zi * NN;
  float* Db = D + (size_t)zi * NN * NN;
  int tid = threadIdx.x;
  int tj = tid & 15, ti = tid >> 4;        // tj fast -> contiguous j stores
  int sc = tid >> 5, su = (tid & 31) * 4;  // staging: c-row, 4-col group

  float acc[8][8];
#pragma unroll
  for (int ii = 0; ii < 8; ++ii)
#pragma unroll
    for (int jj = 0; jj < 8; ++jj) acc[ii][jj] = 0.f;

  for (int c0 = 0; c0 < C; c0 += 8) {
    *(float4*)&Is[sc][su] = *(const float4*)&FTb[(size_t)(c0 + sc) * NN + i0 + su];
    *(float4*)&Js[sc][su] = *(const float4*)&FTb[(size_t)(c0 + sc) * NN + j0 + su];
    __syncthreads();
#pragma unroll
    for (int k = 0; k < 8; ++k) {
      float4 a0 = *(const float4*)&Is[k][ti * 4];
      float4 a1 = *(const float4*)&Is[k][64 + ti * 4];
      float4 b0 = *(const float4*)&Js[k][tj * 4];
      float4 b1 = *(const float4*)&Js[k][64 + tj * 4];
      float ai[8] = {a0.x, a0.y, a0.z, a0.w, a1.x, a1.y, a1.z, a1.w};
      float bj[8] = {b0.x, b0.y, b0.z, b0.w, b1.x, b1.y, b1.z, b1.w};
#pragma unroll
      for (int ii = 0; ii < 8; ++ii)
#pragma unroll
        for (int jj = 0; jj < 8; ++jj) acc[ii][jj] += ai[ii] * bj[jj];
    }
    __syncthreads();
  }

  // epilogue: d = (2*dot - xx_i) - xx_j ; contiguous j-major float4 stores
  float4 xi03 = *(const float4*)&xxb[i0 + ti * 4];
  float4 xi47 = *(const float4*)&xxb[i0 + 64 + ti * 4];
  float4 xj03 = *(const float4*)&xxb[j0 + tj * 4];
  float4 xj47 = *(const float4*)&xxb[j0 + 64 + tj * 4];
  float xi[8] = {xi03.x, xi03.y, xi03.z, xi03.w, xi47.x, xi47.y, xi47.z, xi47.w};
  float xj[8] = {xj03.x, xj03.y, xj03.z, xj03.w, xj47.x, xj47.y, xj47.z, xj47.w};
#pragma unroll
  for (int ii = 0; ii < 8; ++ii) {
    int i_ = i0 + (ii < 4 ? ti * 4 + ii : 64 + ti * 4 + (ii - 4));
    float4 o0, o1;
    float* p0 = (float*)&o0;
    float* p1 = (float*)&o1;
#pragma unroll
    for (int jj = 0; jj < 4; ++jj) p0[jj] = (2.f * acc[ii][jj] - xi[ii]) - xj[jj];
#pragma unroll
    for (int jj = 0; jj < 4; ++jj) p1[jj] = (2.f * acc[ii][jj + 4] - xi[ii]) - xj[jj + 4];
    *(float4*)&Db[(size_t)i_ * NN + j0 + tj * 4] = o0;
    *(float4*)&Db[(size_t)i_ * NN + j0 + 64 + tj * 4] = o1;
  }
}

// ---------------------------------------------------------------------------
// Selection from D: one wave per row; row loaded as 8x float4 in a dedicated
// loop BEFORE the top-3 insert scan. m = i*256 + lane*4 + j; (v desc, m asc)
// butterfly -> exact top-20 of bit-identical D.
__global__ __launch_bounds__(512) void sel_rows(const float* __restrict__ D,
                                                int* __restrict__ idx,
                                                int zmask, int zshift) {
  int zi = blockIdx.x & zmask;
  int wv = threadIdx.x >> 6, lane = threadIdx.x & 63;
  int r = (blockIdx.x >> zshift) * 8 + wv;
  const float* row = D + (size_t)zi * NN * NN + (size_t)r * NN;

  // phase 1: 8 wide loads, no dependent consumer between them
  float4 g[8];
#pragma unroll
  for (int i = 0; i < 8; ++i) g[i] = *(const float4*)&row[i * 256 + lane * 4];

  // phase 2: build per-lane top-3 cache (ascending m per lane)
  float f[32];
  float v1 = -FLT_MAX, v2 = -FLT_MAX, v3 = -FLT_MAX;
  int m1 = 0x7fffffff, m2 = 0x7fffffff, m3 = 0x7fffffff;
#pragma unroll
  for (int i = 0; i < 8; ++i) {
    const float* gv = (const float*)&g[i];
#pragma unroll
    for (int j = 0; j < 4; ++j) {
      float v = gv[j];
      int m = i * 256 + lane * 4 + j;
      f[i * 4 + j] = v;
      if (v > v3) {  // strict >, ascending m -> min-m kept on ties
        if (v > v2) {
          v3 = v2; m3 = m2;
          if (v > v1) { v2 = v1; m2 = m1; v1 = v; m1 = m; }
          else { v2 = v; m2 = m; }
        } else { v3 = v; m3 = m; }
      }
    }
  }

  unsigned used = 0u;
  int navail = 3;
  int myidx = 0;
  for (int it = 0; it < KK; ++it) {
    float bv = v1;
    int bm = m1;
#pragma unroll
    for (int off = 32; off > 0; off >>= 1) {
      float ov = __shfl_xor(bv, off);
      int om = __shfl_xor(bm, off);
      if (ov > bv || (ov == bv && om < bm)) { bv = ov; bm = om; }
    }
    if (lane == it) myidx = bm;
    if (m1 == bm) {  // lane(m) = (m>>2)&63 -> exactly the winning lane
      used |= 1u << (((unsigned)m1 >> 8) * 4 + ((unsigned)m1 & 3));  // slot i*4+j
      v1 = v2; m1 = m2;
      v2 = v3; m2 = m3;
      v3 = -FLT_MAX; m3 = 0x7fffffff;
      if (--navail == 0) {  // rare: rebuild from registers
        v1 = v2 = v3 = -FLT_MAX;
        m1 = m2 = m3 = 0x7fffffff;
#pragma unroll
        for (int s = 0; s < 32; ++s) {
          if (used & (1u << s)) continue;
          float v = f[s];
          int m = (s >> 2) * 256 + lane * 4 + (s & 3);
          if (v > v3) {
            if (v > v2) {
              v3 = v2; m3 = m2;
              if (v > v1) { v2 = v1; m2 = m1; v1 = v; m1 = m; }
              else { v2 = v; m2 = m; }
            } else { v3 = v; m3 = m; }
          }
        }
        navail = 3;
      }
    }
  }
  if (lane < KK) idx[(size_t)zi * NN * KK + (size_t)r * KK + lane] = myidx;
}

// ---------------------------------------------------------------------------
// prep: split w (O,2C) -> Wa (O,C), Wd = Wb - Wa; sv = g/sqrt(v+eps);
//       tq = (bias - m)*sv + be.  (C==0 -> only sv/tq, for the final layer)
__global__ __launch_bounds__(256) void prep_edge(const float* __restrict__ w,
                                                 const float* __restrict__ bias,
                                                 const float* __restrict__ g,
                                                 const float* __restrict__ be,
                                                 const float* __restrict__ m,
                                                 const float* __restrict__ v,
                                                 float* __restrict__ Wa, float* __restrict__ Wd,
                                                 float* __restrict__ sv, float* __restrict__ tq,
                                                 int O, int C) {
  int i = blockIdx.x * 256 + threadIdx.x;
  if (i < O * C) {
    int o = i / C, c = i % C;
    float wa = w[(size_t)o * 2 * C + c];
    float wb = w[(size_t)o * 2 * C + C + c];
    Wa[i] = wa;
    Wd[i] = wb - wa;
  }
  if (i < O) {
    float s = g[i] / sqrtf(v[i] + EPSV);
    sv[i] = s;
    tq[i] = (bias[i] - m[i]) * s + be[i];
  }
}

// ---------------------------------------------------------------------------
// fp32 tiled dual GEMM (layers 1-2: outputs feed kNN -> keep fp32)
template <bool DUAL>
__global__ __launch_bounds__(256) void gemm_pq(const float* __restrict__ F, int ldf, int C,
                                               const float* __restrict__ Wa,
                                               const float* __restrict__ Wd,
                                               const float* __restrict__ sv,
                                               const float* __restrict__ tp,
                                               const float* __restrict__ tq,
                                               float* __restrict__ P, float* __restrict__ Q,
                                               int O) {
  __shared__ __align__(16) float Fs[8][64];
  __shared__ __align__(16) float Was[8][64];
  __shared__ __align__(16) float Wds[8][64];
  int b = blockIdx.x & 7;
  int tt = blockIdx.x >> 3;
  int n0 = (tt & 31) * 64, o0 = (tt >> 5) * 64;
  int tid = threadIdx.x;
  int tn = tid & 15, to = tid >> 4;
  float accP[4][4] = {{0.f}};
  float accQ[4][4] = {{0.f}};
  const float* Fb = F + (size_t)b * NN * ldf;

  for (int c0 = 0; c0 < C; c0 += 8) {
    for (int e = tid; e < 512; e += 256) {
      int n = e >> 3, k = e & 7, c = c0 + k;
      Fs[k][n] = (c < C) ? Fb[(size_t)(n0 + n) * ldf + c] : 0.f;
      Was[k][n] = (c < C) ? Wa[(size_t)(o0 + n) * C + c] : 0.f;
      if (DUAL) Wds[k][n] = (c < C) ? Wd[(size_t)(o0 + n) * C + c] : 0.f;
    }
    __syncthreads();
#pragma unroll
    for (int k = 0; k < 8; ++k) {
      float4 fq = *(const float4*)&Fs[k][tn * 4];
      float4 aq = *(const float4*)&Was[k][to * 4];
      float fa[4] = {fq.x, fq.y, fq.z, fq.w};
      float aa[4] = {aq.x, aq.y, aq.z, aq.w};
#pragma unroll
      for (int i = 0; i < 4; ++i)
#pragma unroll
        for (int j = 0; j < 4; ++j) accP[i][j] += fa[i] * aa[j];
      if (DUAL) {
        float4 dq = *(const float4*)&Wds[k][to * 4];
        float da[4] = {dq.x, dq.y, dq.z, dq.w};
#pragma unroll
        for (int i = 0; i < 4; ++i)
#pragma unroll
          for (int j = 0; j < 4; ++j) accQ[i][j] += fa[i] * da[j];
      }
    }
    __syncthreads();
  }

#pragma unroll
  for (int j = 0; j < 4; ++j) {
    int o = o0 + to * 4 + j;
    float s = sv[o];
    float tpv = (tp != nullptr) ? tp[o] : 0.f;
    float tqv = DUAL ? tq[o] : 0.f;
#pragma unroll
    for (int i = 0; i < 4; ++i) {
      int n = n0 + tn * 4 + i;
      size_t base = ((size_t)b * NN + n) * O + o;
      P[base] = accP[i][j] * s + tpv;
      if (DUAL) Q[base] = accQ[i][j] * s + tqv;
    }
  }
}

// ---------------------------------------------------------------------------
// MFMA bf16 GEMM (fp32 in/out, bf16 staging): layer-3 dual GEMM + final GEMM.
template <int K, bool DUAL>
__global__ __launch_bounds__(256) void gemm_mfma(const float* __restrict__ A, int lda,
                                                 const float* __restrict__ Bw,
                                                 const float* __restrict__ Dw,
                                                 const float* __restrict__ sv,
                                                 const float* __restrict__ tp,
                                                 const float* __restrict__ tq,
                                                 float* __restrict__ P, float* __restrict__ Q,
                                                 int O) {
  __shared__ unsigned short As[128 * 40];
  __shared__ unsigned short Bs[64 * 40];
  __shared__ unsigned short Ds[64 * 40];
  int b = blockIdx.x & 7;
  int tt = blockIdx.x >> 3;
  int nTN = O >> 6;
  int n0 = (tt / nTN) * 128;
  int o0 = (tt % nTN) * 64;
  int tid = threadIdx.x;
  int wv = tid >> 6, lane = tid & 63;
  int wm = wv & 1, wn = wv >> 1;
  const float* Ab = A + (size_t)b * NN * lda;

  f32x4v accP[4][2];
  f32x4v accQ[4][2];
#pragma unroll
  for (int m = 0; m < 4; ++m)
#pragma unroll
    for (int of = 0; of < 2; ++of) {
      accP[m][of] = (f32x4v){0.f, 0.f, 0.f, 0.f};
      if constexpr (DUAL) accQ[m][of] = (f32x4v){0.f, 0.f, 0.f, 0.f};
    }

  for (int ks = 0; ks < K; ks += 32) {
    for (int i = tid; i < 1024; i += 256) {
      int row = i >> 3, k4 = (i & 7) * 4;
      float4 v = *(const float4*)&Ab[(size_t)(n0 + row) * lda + ks + k4];
      uint2 p;
      p.x = pack2bf(v.x, v.y);
      p.y = pack2bf(v.z, v.w);
      *(uint2*)&As[row * 40 + k4] = p;
    }
    for (int i = tid; i < 512; i += 256) {
      int row = i >> 3, k4 = (i & 7) * 4;
      float4 v = *(const float4*)&Bw[(size_t)(o0 + row) * K + ks + k4];
      uint2 p;
      p.x = pack2bf(v.x, v.y);
      p.y = pack2bf(v.z, v.w);
      *(uint2*)&Bs[row * 40 + k4] = p;
      if constexpr (DUAL) {
        float4 d = *(const float4*)&Dw[(size_t)(o0 + row) * K + ks + k4];
        uint2 q;
        q.x = pack2bf(d.x, d.y);
        q.y = pack2bf(d.z, d.w);
        *(uint2*)&Ds[row * 40 + k4] = q;
      }
    }
    __syncthreads();

    int krow = (lane >> 4) * 8;
    bf16x8v af[4], bfr[2], dfr[2];
#pragma unroll
    for (int m = 0; m < 4; ++m)
      af[m] = *(const bf16x8v*)&As[(wm * 64 + m * 16 + (lane & 15)) * 40 + krow];
#pragma unroll
    for (int of = 0; of < 2; ++of) {
      bfr[of] = *(const bf16x8v*)&Bs[(wn * 32 + of * 16 + (lane & 15)) * 40 + krow];
      if constexpr (DUAL)
        dfr[of] = *(const bf16x8v*)&Ds[(wn * 32 + of * 16 + (lane & 15)) * 40 + krow];
    }
#pragma unroll
    for (int m = 0; m < 4; ++m)
#pragma unroll
      for (int of = 0; of < 2; ++of) {
        accP[m][of] = __builtin_amdgcn_mfma_f32_16x16x32_bf16(af[m], bfr[of], accP[m][of], 0, 0, 0);
        if constexpr (DUAL)
          accQ[m][of] = __builtin_amdgcn_mfma_f32_16x16x32_bf16(af[m], dfr[of], accQ[m][of], 0, 0, 0);
      }
    __syncthreads();
  }

#pragma unroll
  for (int of = 0; of < 2; ++of) {
    int o = o0 + wn * 32 + of * 16 + (lane & 15);
    float s = sv[o];
    float bp = (tp != nullptr) ? tp[o] : 0.f;
    float bq = DUAL ? tq[o] : 0.f;
#pragma unroll
    for (int m = 0; m < 4; ++m) {
#pragma unroll
      for (int r = 0; r < 4; ++r) {
        int n = n0 + wm * 64 + m * 16 + (lane >> 4) * 4 + r;
        size_t base = ((size_t)b * NN + n) * O + o;
        P[base] = accP[m][of][r] * s + bp;
        if constexpr (DUAL) Q[base] = accQ[m][of][r] * s + bq;
      }
    }
  }
}

// ---------------------------------------------------------------------------
// gather-max: H[b][n][c0+o] = max(0, max_k (P[b][idx[n][k]][o] + Q[b][n][o]))
template <int O>
__global__ __launch_bounds__(256) void gather_max2(const float* __restrict__ P,
                                                   const float* __restrict__ Q,
                                                   const int* __restrict__ idx,
                                                   float* __restrict__ H, int c0) {
  constexpr int NPB = 256 / O;
  int b = blockIdx.x & 7;
  int sub = threadIdx.x / O, o = threadIdx.x % O;
  int n = (blockIdx.x >> 3) * NPB + sub;
  const int* id = idx + ((size_t)b * NN + n) * KK;
  float q = Q[((size_t)b * NN + n) * O + o];
  float best = -FLT_MAX;
#pragma unroll 4
  for (int k = 0; k < KK; ++k) {
    int j = id[k];
    float v = P[((size_t)b * NN + j) * O + o] + q;
    best = fmaxf(best, v);
  }
  best = fmaxf(best, 0.f);  // relu (before max == after max)
  H[((size_t)b * NN + n) * 448 + c0 + o] = best;
}

// ---------------------------------------------------------------------------
// final reduce: out[b][o] = max over n-chunk, via uint atomicMax (values >= 0)
__global__ __launch_bounds__(256) void reduce_max_part(const float* __restrict__ Z,
                                                       unsigned* __restrict__ out) {
  int b = blockIdx.x & 7;
  int tt = blockIdx.x >> 3;
  int o = (tt & 1) * 256 + threadIdx.x;  // o < 512
  int n0 = (tt >> 1) * 256;
  float m = 0.f;  // relu floor
  for (int n = n0; n < n0 + 256; ++n) {
    float v = Z[((size_t)b * NN + n) * 512 + o];
    m = fmaxf(m, v);
  }
  atomicMax(&out[(size_t)b * 512 + o], __float_as_uint(m));
}

// ---------------------------------------------------------------------------
extern "C" void kernel_launch(void* const* d_in, const int* in_sizes, int n_in,
                              void* d_out, int out_size, void* d_ws, size_t ws_size,
                              hipStream_t stream) {
  const float* x = (const float*)d_in[0];
  const float* w1 = (const float*)d_in[1];
  const float* b1 = (const float*)d_in[2];
  const float* g1 = (const float*)d_in[3];
  const float* be1 = (const float*)d_in[4];
  const float* m1 = (const float*)d_in[5];
  const float* v1 = (const float*)d_in[6];
  const float* w2 = (const float*)d_in[7];
  const float* b2 = (const float*)d_in[8];
  const float* g2 = (const float*)d_in[9];
  const float* be2 = (const float*)d_in[10];
  const float* m2 = (const float*)d_in[11];
  const float* v2 = (const float*)d_in[12];
  const float* w3 = (const float*)d_in[13];
  const float* b3 = (const float*)d_in[14];
  const float* g3 = (const float*)d_in[15];
  const float* be3 = (const float*)d_in[16];
  const float* m3 = (const float*)d_in[17];
  const float* v3 = (const float*)d_in[18];
  const float* wo = (const float*)d_in[19];
  const float* bo = (const float*)d_in[20];
  const float* go = (const float*)d_in[21];
  const float* beo = (const float*)d_in[22];
  const float* mo = (const float*)d_in[23];
  const float* vo = (const float*)d_in[24];

  char* ws = (char*)d_ws;
  float* H = (float*)(ws + 0);              // 29360128
  float* F0 = (float*)(ws + 29360128);      // 196608
  float* xx = (float*)(ws + 29556736);      // 65536
  int* idx = (int*)(ws + 29622272);         // 1310720
  float* P = (float*)(ws + 30932992);       // 16777216
  float* Q = (float*)(ws + 47710208);       // 16777216 (aliased: FT + Z)
  float* Wa = (float*)(ws + 64487424);      // 131072
  float* Wd = (float*)(ws + 64618496);      // 131072
  float* sv = (float*)(ws + 64749568);      // 4096
  float* tq = (float*)(ws + 64753664);      // 4096
  float* Z = P;
  float* FT = Q;

  // D buffer: full 8-batch (134MB) if workspace allows, else 1-batch aliasing P
  bool bigws = ws_size >= (size_t)198975488;
  float* Dbuf = bigws ? (float*)(ws + 64757760) : P;

  dim3 blk(256);

  pack_x<<<dim3(8 * 8), blk, 0, stream>>>(x, F0, xx);

  // ---- layer 1: C=3, O=64  (x is already [b][c][n]; knn1_reg reads it directly)
  prep_edge<<<dim3(1), blk, 0, stream>>>(w1, b1, g1, be1, m1, v1, Wa, Wd, sv, tq, 64, 3);
  knn1_reg<<<dim3(8 * NN / 8), dim3(512), 0, stream>>>(x, xx, idx);
  gemm_pq<true><<<dim3(8 * 32 * 1), blk, 0, stream>>>(F0, 3, 3, Wa, Wd, sv, nullptr, tq, P, Q, 64);
  gather_max2<64><<<dim3(8 * NN / 4), blk, 0, stream>>>(P, Q, idx, H, 0);
  norms_k<<<dim3(8 * 8), blk, 0, stream>>>(H, 448, 64, xx);

  // ---- layer 2: C=64, O=128
  prep_edge<<<dim3(32), blk, 0, stream>>>(w2, b2, g2, be2, m2, v2, Wa, Wd, sv, tq, 128, 64);
  transpose_k<<<dim3(8 * 64 * 2), blk, 0, stream>>>(H, 448, 64, FT);
  if (bigws) {
    dist_gemm<64><<<dim3(8 * 16 * 16), blk, 0, stream>>>(FT, xx, Dbuf, 7, 3);
    sel_rows<<<dim3(8 * NN / 8), dim3(512), 0, stream>>>(Dbuf, idx, 7, 3);
  } else {
    for (int bb = 0; bb < BB; ++bb) {
      dist_gemm<64><<<dim3(16 * 16), blk, 0, stream>>>(FT + (size_t)bb * 64 * NN,
                                                       xx + (size_t)bb * NN, Dbuf, 0, 0);
      sel_rows<<<dim3(NN / 8), dim3(512), 0, stream>>>(Dbuf, idx + (size_t)bb * NN * KK, 0, 0);
    }
  }
  gemm_pq<true><<<dim3(8 * 32 * 2), blk, 0, stream>>>(H, 448, 64, Wa, Wd, sv, nullptr, tq, P, Q, 128);
  gather_max2<128><<<dim3(8 * NN / 2), blk, 0, stream>>>(P, Q, idx, H, 64);
  norms_k<<<dim3(8 * 8), blk, 0, stream>>>(H + 64, 448, 128, xx);

  // ---- layer 3: C=128, O=256
  prep_edge<<<dim3(128), blk, 0, stream>>>(w3, b3, g3, be3, m3, v3, Wa, Wd, sv, tq, 256, 128);
  transpose_k<<<dim3(8 * 64 * 4), blk, 0, stream>>>(H + 64, 448, 128, FT);
  if (bigws) {
    dist_gemm<128><<<dim3(8 * 16 * 16), blk, 0, stream>>>(FT, xx, Dbuf, 7, 3);
    sel_rows<<<dim3(8 * NN / 8), dim3(512), 0, stream>>>(Dbuf, idx, 7, 3);
  } else {
    for (int bb = 0; bb < BB; ++bb) {
      dist_gemm<128><<<dim3(16 * 16), blk, 0, stream>>>(FT + (size_t)bb * 128 * NN,
                                                        xx + (size_t)bb * NN, Dbuf, 0, 0);
      sel_rows<<<dim3(NN / 8), dim3(512), 0, stream>>>(Dbuf, idx + (size_t)bb * NN * KK, 0, 0);
    }
  }
  gemm_mfma<128, true><<<dim3(8 * 16 * 4), blk, 0, stream>>>(H + 64, 448, Wa, Wd, sv, nullptr, tq, P, Q, 256);
  gather_max2<256><<<dim3(8 * NN), blk, 0, stream>>>(P, Q, idx, H, 192);

  // ---- final linear: C=448, O=512 (MFMA bf16; BN folded via sv/tq)
  prep_edge<<<dim3(2), blk, 0, stream>>>(nullptr, bo, go, beo, mo, vo, nullptr, nullptr, sv, tq, 512, 0);
  gemm_mfma<448, false><<<dim3(8 * 16 * 8), blk, 0, stream>>>(H, 448, wo, nullptr, sv, tq, nullptr, Z, nullptr, 512);

  hipMemsetAsync(d_out, 0, (size_t)out_size * sizeof(float), stream);
  reduce_max_part<<<dim3(8 * 16), blk, 0, stream>>>(Z, (unsigned*)d_out);
}